// Round 1
// baseline (210.984 us; speedup 1.0000x reference)
//
#include <hip/hip_runtime.h>
#include <hip/hip_bf16.h>
#include <stdint.h>

// Problem dims (fixed by reference)
#define BB 32
#define CC 256
#define LL 8192
#define NROWS (BB*CC)          // 8192
#define K_RANK ((LL-1)/2)      // 4095 (0-based ascending)
#define BN_EPS 1e-5f
#define LOG_SCALE 6.0205999132796239f   // 20/log2(10)
#define BUCKET_SCALE 42.0f              // 256 buckets over [0, 6.02..)
#define CAND_CAP 768

// ---------------------------------------------------------------------------
// K1: per-row stats: g = mean(|f(u)|), min, max, exact median via bucket-select
// One block per row, 256 threads, 32 elems/thread.
// ---------------------------------------------------------------------------
__global__ __launch_bounds__(256) void k1_stats(const float* __restrict__ x,
                                                float* __restrict__ g_o,
                                                float* __restrict__ med_o,
                                                float* __restrict__ mn_o,
                                                float* __restrict__ mx_o) {
    __shared__ uint32_t sbits[LL];          // 32 KB: |f(u)| bit patterns
    __shared__ uint32_t hist[256];          // 1 KB
    __shared__ float    rsum[256];
    __shared__ float    rmn[256];
    __shared__ float    rmx[256];
    __shared__ uint32_t cand[CAND_CAP];     // 3 KB
    __shared__ uint32_t s_cnt, s_bucket, s_base, s_res;

    const int tid = threadIdx.x;
    const int row = blockIdx.x;
    const float4* __restrict__ xr = (const float4*)(x + (size_t)row * LL);

    hist[tid] = 0u;
    if (tid == 0) { s_cnt = 0u; s_res = 0u; }
    __syncthreads();

    float lsum = 0.f, lmn = 1e30f, lmx = -1e30f;
    #pragma unroll
    for (int k = 0; k < 8; ++k) {
        float4 v = xr[k*256 + tid];
        float uu[4] = {v.x, v.y, v.z, v.w};
        #pragma unroll
        for (int c = 0; c < 4; ++c) {
            float f = LOG_SCALE * __log2f(uu[c] + 1.0f);
            float a = fabsf(f);
            lsum += a;
            lmn = fminf(lmn, a);
            lmx = fmaxf(lmx, a);
            int bk = (int)(a * BUCKET_SCALE);
            bk = min(max(bk, 0), 255);
            atomicAdd(&hist[bk], 1u);
            sbits[(k*256 + tid)*4 + c] = __float_as_uint(a);
        }
    }
    rsum[tid] = lsum; rmn[tid] = lmn; rmx[tid] = lmx;
    __syncthreads();

    // tree reduce sum/min/max
    for (int off = 128; off > 0; off >>= 1) {
        if (tid < off) {
            rsum[tid] += rsum[tid+off];
            rmn[tid]  = fminf(rmn[tid], rmn[tid+off]);
            rmx[tid]  = fmaxf(rmx[tid], rmx[tid+off]);
        }
        __syncthreads();
    }

    // inclusive prefix scan of hist (Hillis-Steele, 256 bins / 256 threads)
    for (int off = 1; off < 256; off <<= 1) {
        uint32_t t = (tid >= off) ? hist[tid-off] : 0u;
        __syncthreads();
        hist[tid] += t;
        __syncthreads();
    }

    // find bucket containing rank K_RANK
    {
        uint32_t cum  = hist[tid];
        uint32_t prev = (tid == 0) ? 0u : hist[tid-1];
        if (cum > (uint32_t)K_RANK && prev <= (uint32_t)K_RANK) {
            s_bucket = (uint32_t)tid;
            s_base   = prev;
        }
    }
    __syncthreads();
    const uint32_t bsel = s_bucket;
    const uint32_t base = s_base;

    // collect candidates of the selected bucket
    #pragma unroll
    for (int k = 0; k < 8; ++k) {
        #pragma unroll
        for (int c = 0; c < 4; ++c) {
            uint32_t bits = sbits[(k*256 + tid)*4 + c];
            float a = __uint_as_float(bits);
            int bk = min(max((int)(a * BUCKET_SCALE), 0), 255);
            if ((uint32_t)bk == bsel) {
                uint32_t idx = atomicAdd(&s_cnt, 1u);
                if (idx < CAND_CAP) cand[idx] = bits;
            }
        }
    }
    __syncthreads();

    // rank-select among candidates (non-negative float bits compare == float compare)
    const uint32_t n  = min(s_cnt, (uint32_t)CAND_CAP);
    const uint32_t kk = (uint32_t)K_RANK - base;
    for (uint32_t t = tid; t < n; t += 256) {
        uint32_t v = cand[t];
        uint32_t lt = 0, eq = 0;
        for (uint32_t j = 0; j < n; ++j) {
            uint32_t w = cand[j];
            lt += (w < v);
            eq += (w == v);
        }
        if (lt <= kk && kk < lt + eq) s_res = v;
    }
    __syncthreads();

    if (tid == 0) {
        g_o[row]  = rsum[0] * (1.0f / LL);
        mn_o[row] = rmn[0];
        mx_o[row] = rmx[0];
        med_o[row] = __uint_as_float(s_res);
    }
}

// ---------------------------------------------------------------------------
// K2: h[b,i] = dot(g[b,:], W1[i,:]) + b1[i]    (32 blocks x 256 threads)
// ---------------------------------------------------------------------------
__global__ __launch_bounds__(256) void k2_h(const float* __restrict__ g,
                                            const float* __restrict__ W1,
                                            const float* __restrict__ b1,
                                            float* __restrict__ h) {
    __shared__ __align__(16) float gs[CC];
    const int b = blockIdx.x, i = threadIdx.x;
    gs[i] = g[b*CC + i];
    __syncthreads();
    const float4* __restrict__ wr = (const float4*)(W1 + (size_t)i*CC);
    const float4* gr = (const float4*)gs;
    float acc = 0.f;
    #pragma unroll 8
    for (int j = 0; j < CC/4; ++j) {
        float4 w = wr[j]; float4 gg = gr[j];
        acc += w.x*gg.x + w.y*gg.y + w.z*gg.z + w.w*gg.w;
    }
    h[b*CC + i] = acc + b1[i];
}

// ---------------------------------------------------------------------------
// K3: BN stats over batch axis. 1 block x 256 threads (thread = channel)
// ---------------------------------------------------------------------------
__global__ __launch_bounds__(256) void k3_bnstats(const float* __restrict__ h,
                                                  float* __restrict__ mu,
                                                  float* __restrict__ rstd) {
    const int i = threadIdx.x;
    float v[BB];
    float s = 0.f;
    #pragma unroll
    for (int b = 0; b < BB; ++b) { v[b] = h[b*CC + i]; s += v[b]; }
    float m = s * (1.0f / BB);
    float vs = 0.f;
    #pragma unroll
    for (int b = 0; b < BB; ++b) { float d = v[b] - m; vs += d*d; }
    mu[i] = m;
    rstd[i] = rsqrtf(vs * (1.0f / BB) + BN_EPS);
}

// ---------------------------------------------------------------------------
// K4: h2 = relu(BN(h)); alpha = sigmoid(h2 @ W2^T + b2); T per (b,c)
// ---------------------------------------------------------------------------
__global__ __launch_bounds__(256) void k4_T(const float* __restrict__ h,
                                            const float* __restrict__ mu,
                                            const float* __restrict__ rstd,
                                            const float* __restrict__ gamma,
                                            const float* __restrict__ beta,
                                            const float* __restrict__ W2,
                                            const float* __restrict__ b2,
                                            const float* __restrict__ med,
                                            const float* __restrict__ mn,
                                            const float* __restrict__ mx,
                                            float* __restrict__ T) {
    __shared__ __align__(16) float h2s[CC];
    const int b = blockIdx.x, i = threadIdx.x;
    float hv = h[b*CC + i];
    float h2 = (hv - mu[i]) * rstd[i] * gamma[i] + beta[i];
    h2 = fmaxf(h2, 0.f);
    h2s[i] = h2;
    __syncthreads();
    const float4* __restrict__ wr = (const float4*)(W2 + (size_t)i*CC);
    const float4* hr = (const float4*)h2s;
    float acc = 0.f;
    #pragma unroll 8
    for (int j = 0; j < CC/4; ++j) {
        float4 w = wr[j]; float4 hh = hr[j];
        acc += w.x*hh.x + w.y*hh.y + w.z*hh.z + w.w*hh.w;
    }
    acc += b2[i];
    float alpha = 1.0f / (1.0f + __expf(-acc));
    const int idx = b*CC + i;
    float m  = med[idx];
    float lo = mn[idx];
    float hi = mx[idx];
    float t = (hi - m > m - lo) ? (m + alpha*(lo - m)) : (m + alpha*(hi - m));
    T[idx] = t;
}

// ---------------------------------------------------------------------------
// K5: out = sign(f) * max(|f| - T[row], 0). One block per row.
// ---------------------------------------------------------------------------
__global__ __launch_bounds__(256) void k5_out(const float* __restrict__ x,
                                              const float* __restrict__ T,
                                              float* __restrict__ out) {
    const int row = blockIdx.x, tid = threadIdx.x;
    const float t = T[row];
    const float4* __restrict__ xr = (const float4*)(x + (size_t)row * LL);
    float4* __restrict__ orow = (float4*)(out + (size_t)row * LL);
    #pragma unroll
    for (int k = 0; k < 8; ++k) {
        float4 v = xr[k*256 + tid];
        float uu[4] = {v.x, v.y, v.z, v.w};
        float oo[4];
        #pragma unroll
        for (int c = 0; c < 4; ++c) {
            float f = LOG_SCALE * __log2f(uu[c] + 1.0f);
            float a = fabsf(f);
            float ns = fmaxf(a - t, 0.f);
            float s = (f > 0.f) ? 1.f : ((f < 0.f) ? -1.f : 0.f);
            oo[c] = s * ns;
        }
        float4 o = make_float4(oo[0], oo[1], oo[2], oo[3]);
        orow[k*256 + tid] = o;
    }
}

// ---------------------------------------------------------------------------
extern "C" void kernel_launch(void* const* d_in, const int* in_sizes, int n_in,
                              void* d_out, int out_size, void* d_ws, size_t ws_size,
                              hipStream_t stream) {
    const float* x     = (const float*)d_in[0];
    const float* W1    = (const float*)d_in[1];
    const float* b1    = (const float*)d_in[2];
    const float* gamma = (const float*)d_in[3];
    const float* beta  = (const float*)d_in[4];
    const float* W2    = (const float*)d_in[5];
    const float* b2    = (const float*)d_in[6];
    float* out = (float*)d_out;

    float* ws   = (float*)d_ws;
    float* g    = ws;                 // 8192
    float* med  = ws + NROWS;         // 8192
    float* mn   = ws + 2*NROWS;       // 8192
    float* mx   = ws + 3*NROWS;       // 8192
    float* h    = ws + 4*NROWS;       // 8192
    float* mu   = ws + 5*NROWS;       // 256
    float* rstd = ws + 5*NROWS + CC;  // 256
    float* T    = ws + 5*NROWS + 2*CC;// 8192

    k1_stats<<<NROWS, 256, 0, stream>>>(x, g, med, mn, mx);
    k2_h    <<<BB,    256, 0, stream>>>(g, W1, b1, h);
    k3_bnstats<<<1,   256, 0, stream>>>(h, mu, rstd);
    k4_T    <<<BB,    256, 0, stream>>>(h, mu, rstd, gamma, beta, W2, b2, med, mn, mx, T);
    k5_out  <<<NROWS, 256, 0, stream>>>(x, T, out);
}

// Round 2
// 177.075 us; speedup vs baseline: 1.1915x; 1.1915x over previous
//
#include <hip/hip_runtime.h>
#include <hip/hip_bf16.h>
#include <stdint.h>

// Problem dims (fixed by reference)
#define BB 32
#define CC 256
#define LL 8192
#define NROWS (BB*CC)          // 8192
#define K_RANK 4095u           // (L-1)/2, 0-based ascending
#define BN_EPS 1e-5f
#define LOG_SCALE 6.0205999132796239f   // 20/log2(10); f(u) = LOG_SCALE*log2(1+u)
#define CAND_CAP 256

// ---------------------------------------------------------------------------
// K1: per-row stats over u (raw input, uniform [0,1)):
//   g = mean f(u)  (needs log per element)
//   min/max/median of x_abs = f(min/max/median of u)  (monotone map)
// Median via exact bucket-select on u (256 uniform buckets -> ~32 cands).
// One block per row, 256 threads, 32 elems/thread held in registers.
// ---------------------------------------------------------------------------
__global__ __launch_bounds__(256) void k1_stats(const float* __restrict__ x,
                                                float* __restrict__ g_o,
                                                float* __restrict__ med_o,
                                                float* __restrict__ mn_o,
                                                float* __restrict__ mx_o) {
    __shared__ uint32_t hist[4][256];     // per-wave privatized histogram (4 KB)
    __shared__ uint32_t hsum[256];        // merged + inclusive scan
    __shared__ float    wpart[3][4];      // per-wave partials: sum,min,max
    __shared__ uint32_t cand[CAND_CAP];   // 1 KB
    __shared__ uint32_t s_cnt, s_bucket, s_base, s_res;

    const int tid  = threadIdx.x;
    const int wid  = tid >> 6;
    const int lane = tid & 63;
    const int row  = blockIdx.x;
    const float4* __restrict__ xr = (const float4*)(x + (size_t)row * LL);

    hist[0][tid] = 0u; hist[1][tid] = 0u; hist[2][tid] = 0u; hist[3][tid] = 0u;
    if (tid == 0) { s_cnt = 0u; s_res = 0u; }
    __syncthreads();

    // load 32 values into registers (fully unrolled -> static indexing)
    float u_[32];
    #pragma unroll
    for (int k = 0; k < 8; ++k) {
        float4 v = xr[k*256 + tid];
        u_[k*4+0] = v.x; u_[k*4+1] = v.y; u_[k*4+2] = v.z; u_[k*4+3] = v.w;
    }

    float lsum = 0.f, lmn = 1e30f, lmx = -1e30f;
    #pragma unroll
    for (int e = 0; e < 32; ++e) {
        float uu = u_[e];
        lsum += __log2f(uu + 1.0f);              // scale by LOG_SCALE once at end
        lmn = fminf(lmn, uu);
        lmx = fmaxf(lmx, uu);
        int bk = (int)(uu * 256.0f);
        bk = min(max(bk, 0), 255);
        atomicAdd(&hist[wid][bk], 1u);
    }

    // wave-level reduce (sum/min/max), then 4 partials
    #pragma unroll
    for (int off = 32; off > 0; off >>= 1) {
        lsum += __shfl_down(lsum, off, 64);
        lmn  = fminf(lmn, __shfl_down(lmn, off, 64));
        lmx  = fmaxf(lmx, __shfl_down(lmx, off, 64));
    }
    if (lane == 0) { wpart[0][wid] = lsum; wpart[1][wid] = lmn; wpart[2][wid] = lmx; }
    __syncthreads();

    // merge per-wave histograms, inclusive prefix scan (Hillis-Steele)
    hsum[tid] = hist[0][tid] + hist[1][tid] + hist[2][tid] + hist[3][tid];
    __syncthreads();
    for (int off = 1; off < 256; off <<= 1) {
        uint32_t t = (tid >= off) ? hsum[tid-off] : 0u;
        __syncthreads();
        hsum[tid] += t;
        __syncthreads();
    }

    // find bucket containing rank K_RANK
    {
        uint32_t cum  = hsum[tid];
        uint32_t prev = (tid == 0) ? 0u : hsum[tid-1];
        if (cum > K_RANK && prev <= K_RANK) { s_bucket = (uint32_t)tid; s_base = prev; }
    }
    __syncthreads();
    const uint32_t bsel = s_bucket;
    const uint32_t base = s_base;

    // collect candidates of the selected bucket from registers
    #pragma unroll
    for (int e = 0; e < 32; ++e) {
        float uu = u_[e];
        int bk = min(max((int)(uu * 256.0f), 0), 255);
        if ((uint32_t)bk == bsel) {
            uint32_t idx = atomicAdd(&s_cnt, 1u);
            if (idx < CAND_CAP) cand[idx] = __float_as_uint(uu);
        }
    }
    __syncthreads();

    // exact rank-select among candidates (nonneg float bits compare == float compare)
    const uint32_t n  = min(s_cnt, (uint32_t)CAND_CAP);
    const uint32_t kk = K_RANK - base;
    for (uint32_t t = tid; t < n; t += 256) {
        uint32_t v = cand[t];
        uint32_t lt = 0, eq = 0;
        for (uint32_t j = 0; j < n; ++j) {
            uint32_t w = cand[j];
            lt += (w < v);
            eq += (w == v);
        }
        if (lt <= kk && kk < lt + eq) s_res = v;
    }
    __syncthreads();

    if (tid == 0) {
        float sum = wpart[0][0] + wpart[0][1] + wpart[0][2] + wpart[0][3];
        float mnu = fminf(fminf(wpart[1][0], wpart[1][1]), fminf(wpart[1][2], wpart[1][3]));
        float mxu = fmaxf(fmaxf(wpart[2][0], wpart[2][1]), fmaxf(wpart[2][2], wpart[2][3]));
        float medu = __uint_as_float(s_res);
        g_o[row]   = LOG_SCALE * sum * (1.0f / LL);
        mn_o[row]  = LOG_SCALE * __log2f(mnu + 1.0f);
        mx_o[row]  = LOG_SCALE * __log2f(mxu + 1.0f);
        med_o[row] = LOG_SCALE * __log2f(medu + 1.0f);
    }
}

// ---------------------------------------------------------------------------
// K2: h[b,i] = dot(g[b,:], W1[i,:]) + b1[i]    (32 blocks x 256 threads)
// ---------------------------------------------------------------------------
__global__ __launch_bounds__(256) void k2_h(const float* __restrict__ g,
                                            const float* __restrict__ W1,
                                            const float* __restrict__ b1,
                                            float* __restrict__ h) {
    __shared__ __align__(16) float gs[CC];
    const int b = blockIdx.x, i = threadIdx.x;
    gs[i] = g[b*CC + i];
    __syncthreads();
    const float4* __restrict__ wr = (const float4*)(W1 + (size_t)i*CC);
    const float4* gr = (const float4*)gs;
    float acc = 0.f;
    #pragma unroll 8
    for (int j = 0; j < CC/4; ++j) {
        float4 w = wr[j]; float4 gg = gr[j];
        acc += w.x*gg.x + w.y*gg.y + w.z*gg.z + w.w*gg.w;
    }
    h[b*CC + i] = acc + b1[i];
}

// ---------------------------------------------------------------------------
// K4: BN stats (recomputed per block, tiny) + relu(BN(h)); alpha = sigmoid(
//     h2 @ W2^T + b2); T per (b,c). 32 blocks x 256 threads.
// ---------------------------------------------------------------------------
__global__ __launch_bounds__(256) void k4_T(const float* __restrict__ h,
                                            const float* __restrict__ gamma,
                                            const float* __restrict__ beta,
                                            const float* __restrict__ W2,
                                            const float* __restrict__ b2,
                                            const float* __restrict__ med,
                                            const float* __restrict__ mn,
                                            const float* __restrict__ mx,
                                            float* __restrict__ T) {
    __shared__ __align__(16) float h2s[CC];
    const int b = blockIdx.x, i = threadIdx.x;

    // BN stats for channel i across the batch (32 coalesced row reads)
    float v[BB];
    float s = 0.f;
    #pragma unroll
    for (int bb = 0; bb < BB; ++bb) { v[bb] = h[bb*CC + i]; s += v[bb]; }
    float m = s * (1.0f / BB);
    float vs = 0.f;
    #pragma unroll
    for (int bb = 0; bb < BB; ++bb) { float d = v[bb] - m; vs += d*d; }
    float rstd = rsqrtf(vs * (1.0f / BB) + BN_EPS);

    float h2 = (v[b] - m) * rstd * gamma[i] + beta[i];
    h2 = fmaxf(h2, 0.f);
    h2s[i] = h2;
    __syncthreads();

    const float4* __restrict__ wr = (const float4*)(W2 + (size_t)i*CC);
    const float4* hr = (const float4*)h2s;
    float acc = 0.f;
    #pragma unroll 8
    for (int j = 0; j < CC/4; ++j) {
        float4 w = wr[j]; float4 hh = hr[j];
        acc += w.x*hh.x + w.y*hh.y + w.z*hh.z + w.w*hh.w;
    }
    acc += b2[i];
    float alpha = 1.0f / (1.0f + __expf(-acc));
    const int idx = b*CC + i;
    float md = med[idx];
    float lo = mn[idx];
    float hi = mx[idx];
    float t = (hi - md > md - lo) ? (md + alpha*(lo - md)) : (md + alpha*(hi - md));
    T[idx] = t;
}

// ---------------------------------------------------------------------------
// K5: out = max(f(u) - T[row], 0).  (f >= 0, T >= 0 => sign logic vanishes)
// ---------------------------------------------------------------------------
__global__ __launch_bounds__(256) void k5_out(const float* __restrict__ x,
                                              const float* __restrict__ T,
                                              float* __restrict__ out) {
    const int row = blockIdx.x, tid = threadIdx.x;
    const float t = T[row];
    const float4* __restrict__ xr = (const float4*)(x + (size_t)row * LL);
    float4* __restrict__ orow = (float4*)(out + (size_t)row * LL);
    #pragma unroll
    for (int k = 0; k < 8; ++k) {
        float4 v = xr[k*256 + tid];
        float4 o;
        o.x = fmaxf(LOG_SCALE * __log2f(v.x + 1.0f) - t, 0.f);
        o.y = fmaxf(LOG_SCALE * __log2f(v.y + 1.0f) - t, 0.f);
        o.z = fmaxf(LOG_SCALE * __log2f(v.z + 1.0f) - t, 0.f);
        o.w = fmaxf(LOG_SCALE * __log2f(v.w + 1.0f) - t, 0.f);
        orow[k*256 + tid] = o;
    }
}

// ---------------------------------------------------------------------------
extern "C" void kernel_launch(void* const* d_in, const int* in_sizes, int n_in,
                              void* d_out, int out_size, void* d_ws, size_t ws_size,
                              hipStream_t stream) {
    const float* x     = (const float*)d_in[0];
    const float* W1    = (const float*)d_in[1];
    const float* b1    = (const float*)d_in[2];
    const float* gamma = (const float*)d_in[3];
    const float* beta  = (const float*)d_in[4];
    const float* W2    = (const float*)d_in[5];
    const float* b2    = (const float*)d_in[6];
    float* out = (float*)d_out;

    float* ws   = (float*)d_ws;
    float* g    = ws;                 // 8192
    float* med  = ws + NROWS;         // 8192
    float* mn   = ws + 2*NROWS;       // 8192
    float* mx   = ws + 3*NROWS;       // 8192
    float* h    = ws + 4*NROWS;       // 8192
    float* T    = ws + 5*NROWS;       // 8192

    k1_stats<<<NROWS, 256, 0, stream>>>(x, g, med, mn, mx);
    k2_h    <<<BB,    256, 0, stream>>>(g, W1, b1, h);
    k4_T    <<<BB,    256, 0, stream>>>(h, gamma, beta, W2, b2, med, mn, mx, T);
    k5_out  <<<NROWS, 256, 0, stream>>>(x, T, out);
}